// Round 10
// baseline (416.593 us; speedup 1.0000x reference)
//
#include <hip/hip_runtime.h>
#include <hip/hip_bf16.h>

#define Nn 8
#define Cc 64
#define Tt 16
#define Hh 56
#define Ww 56

typedef __bf16 bf16x8 __attribute__((ext_vector_type(8)));
typedef float f32x4 __attribute__((ext_vector_type(4)));
typedef unsigned short u16;
typedef unsigned int u32;

__device__ __forceinline__ u16 f32_to_bf16(float f) {
    u32 u = __float_as_uint(f);
    u32 r = (u + 0x7FFFu + ((u >> 16) & 1u)) >> 16;
    return (u16)r;
}
__device__ __forceinline__ float bf16_to_f32(u16 h) {
    return __uint_as_float(((u32)h) << 16);
}

// async global->LDS, 16B per lane, dst = wave-uniform base + lane*16
__device__ __forceinline__ void gload16(const void* gsrc, void* lds) {
    __builtin_amdgcn_global_load_lds(
        (const __attribute__((address_space(1))) u32*)gsrc,
        (__attribute__((address_space(3))) u32*)lds, 16, 0, 0);
}

// ---------------- P0: weights -> bf16 hi/lo in [tap][co][ci]; +zeros page ----
__global__ __launch_bounds__(256) void prep_w_kernel(
    const float* __restrict__ w1, const float* __restrict__ w2,
    u16* __restrict__ w1h, u16* __restrict__ w1l,
    u16* __restrict__ w2h, u16* __restrict__ w2l,
    u16* __restrict__ zpage)
{
    int idx = blockIdx.x * 256 + threadIdx.x;
    if (idx >= 221184) {                            // zeros page: 256 x 16B = 4KB
        ((uint4*)zpage)[idx - 221184] = make_uint4(0, 0, 0, 0);
        return;
    }
    int conv = idx / 110592;
    int rem  = idx % 110592;
    int tap  = rem >> 12;
    int co   = (rem >> 6) & 63;
    int ci   = rem & 63;
    const float* w = conv ? w2 : w1;
    float v = w[co * 1728 + ci * 27 + tap];
    u16 hi = f32_to_bf16(v);
    u16 lo = f32_to_bf16(v - bf16_to_f32(hi));
    int dst = tap * 4096 + co * 64 + ci;
    if (conv) { w2h[dst] = hi; w2l[dst] = lo; }
    else      { w1h[dst] = hi; w1l[dst] = lo; }
}

// ---------------- P1: x -> xh/xl bf16 in [n][t][h][w][ci] ----------------
__global__ __launch_bounds__(256) void split_x_kernel(
    const float* __restrict__ x, u16* __restrict__ xh, u16* __restrict__ xl)
{
    __shared__ float tile[Cc][Hh + 1];
    const int tid = threadIdx.x;
    const int bid = blockIdx.x;           // = (n*Tt + t)*Hh + h
    const int h = bid % Hh;
    const int t = (bid / Hh) % Tt;
    const int n = bid / (Hh * Tt);
    for (int it = 0; it < 14; ++it) {
        int id = it * 256 + tid;
        int ci = id / Ww, w = id % Ww;
        tile[ci][w] = x[(((size_t)(n * Cc + ci) * Tt + t) * Hh + h) * Ww + w];
    }
    __syncthreads();
    const size_t obase = (size_t)bid * (Ww * Cc);
    for (int it = 0; it < 7; ++it) {
        int j = it * 256 + tid;
        int w = j >> 5, ci0 = (j & 31) << 1;
        float f0 = tile[ci0][w], f1 = tile[ci0 + 1][w];
        u16 h0 = f32_to_bf16(f0), h1 = f32_to_bf16(f1);
        u16 l0 = f32_to_bf16(f0 - bf16_to_f32(h0));
        u16 l1 = f32_to_bf16(f1 - bf16_to_f32(h1));
        size_t o = obase + (size_t)w * Cc + ci0;
        *(ushort2*)(xh + o) = make_ushort2(h0, h1);
        *(ushort2*)(xl + o) = make_ushort2(l0, l1);
    }
}

// ---------------- conv kernels ----------------
// conv1 (w-split): A slice = 34 rows (w-pos w0-1..w0+32) x 64B. 20 units (10 hh x hi/lo).
// LDS linear chunk fi -> byte fi*16 (global_load_lds). XOR swizzle on global SOURCE;
// reads apply the same XOR (frag_ptr). B: 9 taps x 64co x 32ci, hi then lo (restaged).
#define S1B   2176                    // 34*64
#define A1_B  (20 * S1B)              // 43520 (2720 chunks)
#define B1_B  (9 * 4096)              // 36864 (2304 chunks)
#define C1_SMEM (A1_B + B1_B)         // 80384 -> 2 blocks/CU
// conv2 (unchanged from R9): 58-row slices
#define SLICE_B 3712                  // 58*64
#define C2_BOFF 40960
#define C2_SMEM 81920                 // 2 blocks/CU

__device__ __forceinline__ const bf16x8* frag_ptr2(const char* base, int row, int g) {
    int col = (g * 16) ^ (((row >> 1) & 3) << 4);
    return (const bf16x8*)(base + row * 64 + col);
}

__global__ __launch_bounds__(512, 2) void conv1_mfma_kernel(
    const u16* __restrict__ xh, const u16* __restrict__ xl,
    const u16* __restrict__ w1h, const u16* __restrict__ w1l,
    const float* __restrict__ b1, const float* __restrict__ e1,
    const u16* __restrict__ zpage, u16* __restrict__ res1)
{
    __shared__ __align__(16) char smem[C1_SMEM];
    char* As = smem;
    char* Bs = smem + A1_B;

    const int tid = threadIdx.x;
    const int l = tid & 63, wid = tid >> 6;
    const int g = l >> 4, r15 = l & 15;
    const int wbase = tid & ~63;                    // wave-uniform
    // XCD-chunked swizzle: 1792 wgs = 8 XCDs x 224 contiguous
    const int bid = (blockIdx.x & 7) * 224 + (blockIdx.x >> 3);
    const int w0 = (bid & 1) * 28;                  // w-half
    const int r2 = bid >> 1;
    const int hb = r2 % 7;
    const int t  = (r2 / 7) % Tt;
    const int n  = r2 / (7 * Tt);
    const int h0 = hb * 8;

    f32x4 acc[2][4] = {};

    // B stage helper pattern (2304 chunks): it 0..3 full, it 4 waves 0-3 only
#pragma unroll 1
    for (int cih = 0; cih < 2; ++cih) {
#pragma unroll 1
      for (int kd = 0; kd < 3; ++kd) {
        const int td = t + kd - 1;
        if (td < 0 || td >= Tt) continue;           // block-uniform skip
        __builtin_amdgcn_sched_barrier(0);
        __builtin_amdgcn_s_barrier();               // prev slab's LDS reads done
        __builtin_amdgcn_sched_barrier(0);
        // stage A: 2720 chunks (6 iters, tail predicated)
        {
          const size_t tdbase = (size_t)(n * Tt + td) * ((size_t)Hh * Ww * Cc);
#pragma unroll
          for (int it = 0; it < 6; ++it) {
            int fi = it * 512 + tid;
            int u = fi / 136, c = fi - u * 136;
            int r = c >> 2, slot = c & 3;
            int s = u >> 1, half = u & 1;
            int hh = h0 - 1 + s;
            int pos = w0 - 1 + r;
            int slog = slot ^ ((r >> 1) & 3);       // pre-swizzled source
            const u16* src = (half ? xl : xh) + tdbase
                + ((size_t)hh * Ww + pos) * Cc + cih * 32 + slog * 8;
            bool valid = (fi < 2720) & (hh >= 0) & (hh < Hh) & (pos >= 0) & (pos < Ww);
            if (!valid) src = zpage;
            if (fi < 2720) gload16(src, As + (it * 512 + wbase) * 16);
          }
        }
        // stage B-hi: 2304 chunks
        {
#pragma unroll
          for (int it = 0; it < 5; ++it) {
            int fi = it * 512 + tid;
            int u = fi >> 8, c = fi & 255;
            int co = c >> 2, slot = c & 3;
            int slog = slot ^ ((co >> 1) & 3);
            const u16* src = w1h + (kd * 9 + u) * 4096 + co * 64 + cih * 32 + slog * 8;
            if (fi < 2304) gload16(src, Bs + (it * 512 + wbase) * 16);
          }
        }
        asm volatile("s_waitcnt vmcnt(0)" ::: "memory");
        __builtin_amdgcn_s_barrier();
        __builtin_amdgcn_sched_barrier(0);
        // sub-phase 1: ah*bh + al*bh (9 taps x 16 MFMA)
        const char* Ab0 = As + (size_t)wid * 2 * S1B;
#pragma unroll
        for (int kh = 0; kh < 3; ++kh) {
          const char* Ab = Ab0 + (size_t)kh * 2 * S1B;
#pragma unroll
          for (int kw = 0; kw < 3; ++kw) {
            const int tap9 = kh * 3 + kw;
            bf16x8 ah[2], al[2], bh[4];
#pragma unroll
            for (int m = 0; m < 2; ++m) {
              int row = r15 + 16 * m + kw;
              ah[m] = *frag_ptr2(Ab, row, g);
              al[m] = *frag_ptr2(Ab + S1B, row, g);
            }
#pragma unroll
            for (int nt = 0; nt < 4; ++nt)
              bh[nt] = *frag_ptr2(Bs + tap9 * 4096, r15 + 16 * nt, g);
#pragma unroll
            for (int m = 0; m < 2; ++m)
#pragma unroll
              for (int nt = 0; nt < 4; ++nt) {
                acc[m][nt] = __builtin_amdgcn_mfma_f32_16x16x32_bf16(ah[m], bh[nt], acc[m][nt], 0, 0, 0);
                acc[m][nt] = __builtin_amdgcn_mfma_f32_16x16x32_bf16(al[m], bh[nt], acc[m][nt], 0, 0, 0);
              }
          }
        }
        __builtin_amdgcn_sched_barrier(0);
        __builtin_amdgcn_s_barrier();               // all waves done reading B-hi
        __builtin_amdgcn_sched_barrier(0);
        // restage B-lo into same region
        {
#pragma unroll
          for (int it = 0; it < 5; ++it) {
            int fi = it * 512 + tid;
            int u = fi >> 8, c = fi & 255;
            int co = c >> 2, slot = c & 3;
            int slog = slot ^ ((co >> 1) & 3);
            const u16* src = w1l + (kd * 9 + u) * 4096 + co * 64 + cih * 32 + slog * 8;
            if (fi < 2304) gload16(src, Bs + (it * 512 + wbase) * 16);
          }
        }
        asm volatile("s_waitcnt vmcnt(0)" ::: "memory");
        __builtin_amdgcn_s_barrier();
        __builtin_amdgcn_sched_barrier(0);
        // sub-phase 2: ah*bl
#pragma unroll
        for (int kh = 0; kh < 3; ++kh) {
          const char* Ab = Ab0 + (size_t)kh * 2 * S1B;
#pragma unroll
          for (int kw = 0; kw < 3; ++kw) {
            const int tap9 = kh * 3 + kw;
            bf16x8 ah[2], bl[4];
#pragma unroll
            for (int m = 0; m < 2; ++m)
              ah[m] = *frag_ptr2(Ab, r15 + 16 * m + kw, g);
#pragma unroll
            for (int nt = 0; nt < 4; ++nt)
              bl[nt] = *frag_ptr2(Bs + tap9 * 4096, r15 + 16 * nt, g);
#pragma unroll
            for (int m = 0; m < 2; ++m)
#pragma unroll
              for (int nt = 0; nt < 4; ++nt)
                acc[m][nt] = __builtin_amdgcn_mfma_f32_16x16x32_bf16(ah[m], bl[nt], acc[m][nt], 0, 0, 0);
          }
        }
      }
    }
    // epilogue: bias, BFP quant, relu, store bf16 (exact)
    const int h = h0 + wid;
    const size_t rowbase = ((size_t)(n * Tt + t) * Hh + h) * ((size_t)Ww * Cc);
#pragma unroll
    for (int nt = 0; nt < 4; ++nt) {
      int co = 16 * nt + r15;
      float e = e1[co];
      float sc = exp2f(7.0f - e), inv = exp2f(e - 7.0f);
      float bias = b1[co];
#pragma unroll
      for (int m = 0; m < 2; ++m)
#pragma unroll
        for (int j = 0; j < 4; ++j) {
          int wl = 16 * m + 4 * g + j;
          if (wl < 28) {
            float v = acc[m][nt][j] + bias;
            float q = rintf(v * sc);
            q = fminf(fmaxf(q, -127.f), 127.f);
            v = fmaxf(q * inv, 0.0f);
            res1[rowbase + (size_t)(w0 + wl) * Cc + co] = f32_to_bf16(v);
          }
        }
    }
}

// conv2: single-pass (a.w2h), 80KB LDS -> 2 blocks/CU (unchanged from R9)
__global__ __launch_bounds__(512, 2) void conv2_mfma_kernel(
    const u16* __restrict__ a, const u16* __restrict__ w2h,
    const float* __restrict__ b2, const float* __restrict__ e2,
    const float* __restrict__ x, const u16* __restrict__ zpage,
    float* __restrict__ out)
{
    __shared__ __align__(16) char smem[C2_SMEM];
    char* As = smem;
    char* Bs = smem + C2_BOFF;

    const int tid = threadIdx.x;
    const int l = tid & 63, wid = tid >> 6;
    const int g = l >> 4, r15 = l & 15;
    const int wbase = tid & ~63;
    const int bid = (blockIdx.x & 7) * 112 + (blockIdx.x >> 3);
    const int hb = bid % 7;
    const int t  = (bid / 7) % Tt;
    const int n  = bid / (7 * Tt);
    const int h0 = hb * 8;

    f32x4 acc[4][4] = {};

#pragma unroll 1
    for (int cih = 0; cih < 2; ++cih) {
#pragma unroll 1
      for (int kd = 0; kd < 3; ++kd) {
        const int td = t + kd - 1;
        if (td < 0 || td >= Tt) continue;
        __builtin_amdgcn_sched_barrier(0);
        __builtin_amdgcn_s_barrier();
        __builtin_amdgcn_sched_barrier(0);
        // stage A: 2320 chunks
        {
          const size_t tdbase = (size_t)(n * Tt + td) * ((size_t)Hh * Ww * Cc);
#pragma unroll
          for (int it = 0; it < 5; ++it) {
            int fi = it * 512 + tid;
            int u = fi / 232, c = fi - u * 232;
            int r = c >> 2, slot = c & 3;
            int hh = h0 - 1 + u;
            int slog = slot ^ ((r >> 1) & 3);
            const u16* src = a + tdbase
                + ((size_t)hh * Ww + (r - 1)) * Cc + cih * 32 + slog * 8;
            bool valid = (fi < 2320) & (hh >= 0) & (hh < Hh) & (r >= 1) & (r <= Ww);
            if (!valid) src = zpage;
            gload16(src, As + (it * 512 + wbase) * 16);
          }
        }
        // stage B: 2304 chunks
        {
#pragma unroll
          for (int it = 0; it < 5; ++it) {
            int fi = it * 512 + tid;
            int u = fi >> 8, c = fi & 255;
            int co = c >> 2, slot = c & 3;
            int slog = slot ^ ((co >> 1) & 3);
            const u16* src = w2h + (kd * 9 + u) * 4096 + co * 64 + cih * 32 + slog * 8;
            if (fi >= 2304) src = zpage;
            gload16(src, Bs + (it * 512 + wbase) * 16);
          }
        }
        asm volatile("s_waitcnt vmcnt(0)" ::: "memory");
        __builtin_amdgcn_s_barrier();
        __builtin_amdgcn_sched_barrier(0);
        const char* Ab0 = As + (size_t)wid * SLICE_B;
#pragma unroll
        for (int kh = 0; kh < 3; ++kh) {
          const char* Ab = Ab0 + (size_t)kh * SLICE_B;
#pragma unroll
          for (int kw = 0; kw < 3; ++kw) {
            const int tap9 = kh * 3 + kw;
            bf16x8 af[4], bh[4];
#pragma unroll
            for (int m = 0; m < 4; ++m)
              af[m] = *frag_ptr2(Ab, r15 + 16 * m + kw, g);
#pragma unroll
            for (int nt = 0; nt < 4; ++nt)
              bh[nt] = *frag_ptr2(Bs + tap9 * 4096, r15 + 16 * nt, g);
#pragma unroll
            for (int m = 0; m < 4; ++m)
#pragma unroll
              for (int nt = 0; nt < 4; ++nt)
                acc[m][nt] = __builtin_amdgcn_mfma_f32_16x16x32_bf16(af[m], bh[nt], acc[m][nt], 0, 0, 0);
          }
        }
      }
    }
    // epilogue: conv-quant + identity-quant + relu -> f32 out (NCDHW)
    const int h = h0 + wid;
#pragma unroll
    for (int nt = 0; nt < 4; ++nt) {
      int co = 16 * nt + r15;
      float e = e2[co];
      float sc = exp2f(7.0f - e), inv = exp2f(e - 7.0f);
      float bias = b2[co];
#pragma unroll
      for (int m = 0; m < 4; ++m)
#pragma unroll
        for (int j = 0; j < 4; ++j) {
          int w = 16 * m + 4 * g + j;
          if (w < Ww) {
            float v = acc[m][nt][j] + bias;
            float q = rintf(v * sc);
            q = fminf(fmaxf(q, -127.f), 127.f);
            v = q * inv;
            size_t xi = (((size_t)(n * Cc + co) * Tt + t) * Hh + h) * Ww + w;
            float xv = x[xi];
            float qx = rintf(xv * sc);
            qx = fminf(fmaxf(qx, -127.f), 127.f);
            out[xi] = fmaxf(qx * inv + v, 0.0f);
          }
        }
    }
}

extern "C" void kernel_launch(void* const* d_in, const int* in_sizes, int n_in,
                              void* d_out, int out_size, void* d_ws, size_t ws_size,
                              hipStream_t stream) {
    const float* x  = (const float*)d_in[0];
    const float* w1 = (const float*)d_in[1];
    const float* b1 = (const float*)d_in[2];
    const float* w2 = (const float*)d_in[3];
    const float* b2 = (const float*)d_in[4];
    const float* e1 = (const float*)d_in[5];
    const float* e2 = (const float*)d_in[6];

    const size_t NE = 25690112;            // out elems = 8*64*16*56*56
    u16* xh = (u16*)d_out;                 // d_out doubles as xh/xl scratch
    u16* xl = xh + NE;
    char* ws = (char*)d_ws;
    u16* w1h = (u16*)(ws);
    u16* w1l = (u16*)(ws + 221184);
    u16* w2h = (u16*)(ws + 442368);
    u16* w2l = (u16*)(ws + 663552);
    u16* zpage = (u16*)(ws + 884736);      // 4KB zeros
    u16* res1  = (u16*)(ws + 888832);      // 51.4 MB

    prep_w_kernel<<<865, 256, 0, stream>>>(w1, w2, w1h, w1l, w2h, w2l, zpage);
    split_x_kernel<<<Nn * Tt * Hh, 256, 0, stream>>>(x, xh, xl);
    conv1_mfma_kernel<<<1792, 512, 0, stream>>>(xh, xl, w1h, w1l, b1, e1, zpage, res1);
    conv2_mfma_kernel<<<896, 512, 0, stream>>>(res1, w2h, b2, e2, x, zpage, (float*)d_out);
}

// Round 11
// 354.638 us; speedup vs baseline: 1.1747x; 1.1747x over previous
//
#include <hip/hip_runtime.h>
#include <hip/hip_bf16.h>

#define Nn 8
#define Cc 64
#define Tt 16
#define Hh 56
#define Ww 56

typedef __bf16 bf16x8 __attribute__((ext_vector_type(8)));
typedef float f32x16 __attribute__((ext_vector_type(16)));
typedef unsigned short u16;
typedef unsigned int u32;

__device__ __forceinline__ u16 f32_to_bf16(float f) {
    u32 u = __float_as_uint(f);
    u32 r = (u + 0x7FFFu + ((u >> 16) & 1u)) >> 16;
    return (u16)r;
}
__device__ __forceinline__ float bf16_to_f32(u16 h) {
    return __uint_as_float(((u32)h) << 16);
}

// async global->LDS, 16B per lane, dst = wave-uniform base + lane*16
__device__ __forceinline__ void gload16(const void* gsrc, void* lds) {
    __builtin_amdgcn_global_load_lds(
        (const __attribute__((address_space(1))) u32*)gsrc,
        (__attribute__((address_space(3))) u32*)lds, 16, 0, 0);
}

// ---------------- P0: weights -> bf16 hi/lo in [tap][co][ci]; +zeros page ----
__global__ __launch_bounds__(256) void prep_w_kernel(
    const float* __restrict__ w1, const float* __restrict__ w2,
    u16* __restrict__ w1h, u16* __restrict__ w1l,
    u16* __restrict__ w2h, u16* __restrict__ w2l,
    u16* __restrict__ zpage)
{
    int idx = blockIdx.x * 256 + threadIdx.x;
    if (idx >= 221184) {                            // zeros page: 256 x 16B = 4KB
        ((uint4*)zpage)[idx - 221184] = make_uint4(0, 0, 0, 0);
        return;
    }
    int conv = idx / 110592;
    int rem  = idx % 110592;
    int tap  = rem >> 12;
    int co   = (rem >> 6) & 63;
    int ci   = rem & 63;
    const float* w = conv ? w2 : w1;
    float v = w[co * 1728 + ci * 27 + tap];
    u16 hi = f32_to_bf16(v);
    u16 lo = f32_to_bf16(v - bf16_to_f32(hi));
    int dst = tap * 4096 + co * 64 + ci;
    if (conv) { w2h[dst] = hi; w2l[dst] = lo; }
    else      { w1h[dst] = hi; w1l[dst] = lo; }
}

// ---------------- P1: x -> xh bf16 in [n][t][h][w][ci] (hi only) ----------------
__global__ __launch_bounds__(256) void split_x_kernel(
    const float* __restrict__ x, u16* __restrict__ xh)
{
    __shared__ float tile[Cc][Hh + 1];
    const int tid = threadIdx.x;
    const int bid = blockIdx.x;           // = (n*Tt + t)*Hh + h
    const int h = bid % Hh;
    const int t = (bid / Hh) % Tt;
    const int n = bid / (Hh * Tt);
    for (int it = 0; it < 14; ++it) {
        int id = it * 256 + tid;
        int ci = id / Ww, w = id % Ww;
        tile[ci][w] = x[(((size_t)(n * Cc + ci) * Tt + t) * Hh + h) * Ww + w];
    }
    __syncthreads();
    const size_t obase = (size_t)bid * (Ww * Cc);
    for (int it = 0; it < 7; ++it) {
        int j = it * 256 + tid;
        int w = j >> 5, ci0 = (j & 31) << 1;
        u16 h0 = f32_to_bf16(tile[ci0][w]);
        u16 h1 = f32_to_bf16(tile[ci0 + 1][w]);
        *(ushort2*)(xh + obase + (size_t)w * Cc + ci0) = make_ushort2(h0, h1);
    }
}

// ---------------- conv kernels ----------------
// A slice: 58 rows (x-pos -1..56) x 64B (32 ci). Chunk fi -> LDS byte fi*16 (LINEAR).
// XOR swizzle on global SOURCE index; reads apply same XOR.
#define SLICE_B 3712                  // 58*64
#define A1_BUF 40960                  // 2320 chunks data + pad (one cih, xh only)
#define B1_OFF (2 * A1_BUF)           // 81920
#define C1_SMEM (81920 + 73728)       // 155648: A dbuf + B(hi+lo, 18*4096)
#define C2_BOFF 40960
#define C2_SMEM 81920                 // 2 blocks/CU

__device__ __forceinline__ const bf16x8* frag_ptr(const char* base, int row, int slot) {
    int col = (slot * 16) ^ (((row >> 1) & 3) << 4);
    return (const bf16x8*)(base + row * 64 + col);
}

// conv1: 2-pass (xh*wh + xh*wl), 32x32x16 MFMA, A double-buffered issue-early pipeline
__global__ __launch_bounds__(512, 1) void conv1_mfma_kernel(
    const u16* __restrict__ xh,
    const u16* __restrict__ w1h, const u16* __restrict__ w1l,
    const float* __restrict__ b1, const float* __restrict__ e1,
    const u16* __restrict__ zpage, u16* __restrict__ res1)
{
    __shared__ __align__(16) char smem[C1_SMEM];
    char* Bs = smem + B1_OFF;

    const int tid = threadIdx.x;
    const int l = tid & 63, wid = tid >> 6;
    const int l31 = l & 31, hi5 = l >> 5;
    const int wbase = tid & ~63;                    // wave-uniform
    const int bid = (blockIdx.x & 7) * 112 + (blockIdx.x >> 3);
    const int hb = bid % 7;
    const int t  = (bid / 7) % Tt;
    const int n  = bid / (7 * Tt);
    const int h0 = hb * 8;

    f32x16 acc[2][2] = {};

    char* Acur = smem;
    char* Anxt = smem + A1_BUF;

    // issue A gloads for slab (cih,kd) into dst (2560 chunks incl. pad)
    auto ISSUE_A = [&](int cih, int kd, char* dst) {
        const int td = t + kd - 1;
        const bool tdv = (td >= 0 && td < Tt);
        const size_t tdbase = (size_t)(n * Tt + (tdv ? td : 0)) * ((size_t)Hh * Ww * Cc);
#pragma unroll
        for (int it = 0; it < 5; ++it) {
            int fi = it * 512 + tid;
            int u = fi / 232, c = fi - u * 232;
            int r = c >> 2, slot = c & 3;
            int hh = h0 - 1 + u;
            int slog = slot ^ ((r >> 1) & 3);       // pre-swizzled source
            const u16* src = xh + tdbase
                + ((size_t)hh * Ww + (r - 1)) * Cc + cih * 32 + slog * 8;
            bool valid = tdv & (fi < 2320) & (hh >= 0) & (hh < Hh) & (r >= 1) & (r <= Ww);
            if (!valid) src = zpage;
            gload16(src, dst + (it * 512 + wbase) * 16);
        }
    };
    // issue B gloads for slab (cih,kd): 18 units (hi 9 taps, lo 9 taps)
    auto ISSUE_B = [&](int cih, int kd) {
#pragma unroll
        for (int it = 0; it < 9; ++it) {
            int fi = it * 512 + tid;
            int u = fi >> 8, c = fi & 255;
            int co = c >> 2, slot = c & 3;
            int slog = slot ^ ((co >> 1) & 3);
            int hl = (u >= 9), tap9 = u - 9 * hl;
            const u16* src = (hl ? w1l : w1h)
                + (kd * 9 + tap9) * 4096 + co * 64 + cih * 32 + slog * 8;
            gload16(src, Bs + (it * 512 + wbase) * 16);
        }
    };

    // prologue
    ISSUE_A(0, 0, Acur);
    ISSUE_B(0, 0);
    asm volatile("s_waitcnt vmcnt(0)" ::: "memory");
    __builtin_amdgcn_s_barrier();
    __builtin_amdgcn_sched_barrier(0);

#pragma unroll 1
    for (int i = 0; i < 6; ++i) {
        if (i < 5) ISSUE_A((i + 1) / 3, (i + 1) % 3, Anxt);   // early-issue next A
        __builtin_amdgcn_sched_barrier(0);
        // compute slab i from Acur, Bs: 9 taps x 16 MFMA(32x32) per wave
        const char* Ab0 = Acur + (size_t)wid * SLICE_B;
#pragma unroll
        for (int kh = 0; kh < 3; ++kh) {
            const char* Ab = Ab0 + (size_t)kh * SLICE_B;
#pragma unroll
            for (int kw = 0; kw < 3; ++kw) {
                const int tap9 = kh * 3 + kw;
                bf16x8 a[2][2], bh[2][2], bl[2][2];
#pragma unroll
                for (int m = 0; m < 2; ++m)
#pragma unroll
                    for (int kk = 0; kk < 2; ++kk)
                        a[m][kk] = *frag_ptr(Ab, l31 + 32 * m + kw, kk * 2 + hi5);
#pragma unroll
                for (int nt = 0; nt < 2; ++nt)
#pragma unroll
                    for (int kk = 0; kk < 2; ++kk) {
                        int co = l31 + 32 * nt;
                        bh[nt][kk] = *frag_ptr(Bs + tap9 * 4096, co, kk * 2 + hi5);
                        bl[nt][kk] = *frag_ptr(Bs + (9 + tap9) * 4096, co, kk * 2 + hi5);
                    }
#pragma unroll
                for (int m = 0; m < 2; ++m)
#pragma unroll
                    for (int nt = 0; nt < 2; ++nt)
#pragma unroll
                        for (int kk = 0; kk < 2; ++kk)
                            acc[m][nt] = __builtin_amdgcn_mfma_f32_32x32x16_bf16(
                                a[m][kk], bh[nt][kk], acc[m][nt], 0, 0, 0);
#pragma unroll
                for (int m = 0; m < 2; ++m)
#pragma unroll
                    for (int nt = 0; nt < 2; ++nt)
#pragma unroll
                        for (int kk = 0; kk < 2; ++kk)
                            acc[m][nt] = __builtin_amdgcn_mfma_f32_32x32x16_bf16(
                                a[m][kk], bl[nt][kk], acc[m][nt], 0, 0, 0);
            }
        }
        __builtin_amdgcn_sched_barrier(0);
        __builtin_amdgcn_s_barrier();               // all waves done reading Acur, Bs
        if (i < 5) {
            ISSUE_B((i + 1) / 3, (i + 1) % 3);      // refill Bs
            asm volatile("s_waitcnt vmcnt(0)" ::: "memory");  // B[i+1] AND A[i+1] landed
            __builtin_amdgcn_s_barrier();
            __builtin_amdgcn_sched_barrier(0);
        }
        char* tmp = Acur; Acur = Anxt; Anxt = tmp;
    }

    // epilogue: bias, BFP quant, relu, store bf16 (exact)
    const int h = h0 + wid;
    const size_t rowbase = ((size_t)(n * Tt + t) * Hh + h) * ((size_t)Ww * Cc);
#pragma unroll
    for (int nt = 0; nt < 2; ++nt) {
        int co = 32 * nt + l31;
        float e = e1[co];
        float sc = exp2f(7.0f - e), inv = exp2f(e - 7.0f);
        float bias = b1[co];
#pragma unroll
        for (int m = 0; m < 2; ++m)
#pragma unroll
            for (int reg = 0; reg < 16; ++reg) {
                int w = 32 * m + (reg & 3) + 8 * (reg >> 2) + 4 * hi5;
                if (w < Ww) {
                    float v = acc[m][nt][reg] + bias;
                    float q = rintf(v * sc);
                    q = fminf(fmaxf(q, -127.f), 127.f);
                    v = fmaxf(q * inv, 0.0f);
                    res1[rowbase + (size_t)w * Cc + co] = f32_to_bf16(v);
                }
            }
    }
}

// conv2: single-pass (a.w2h), 32x32x16 MFMA, 80KB LDS -> 2 blocks/CU
__global__ __launch_bounds__(512, 2) void conv2_mfma_kernel(
    const u16* __restrict__ a, const u16* __restrict__ w2h,
    const float* __restrict__ b2, const float* __restrict__ e2,
    const float* __restrict__ x, const u16* __restrict__ zpage,
    float* __restrict__ out)
{
    __shared__ __align__(16) char smem[C2_SMEM];
    char* As = smem;
    char* Bs = smem + C2_BOFF;

    const int tid = threadIdx.x;
    const int l = tid & 63, wid = tid >> 6;
    const int l31 = l & 31, hi5 = l >> 5;
    const int wbase = tid & ~63;
    const int bid = (blockIdx.x & 7) * 112 + (blockIdx.x >> 3);
    const int hb = bid % 7;
    const int t  = (bid / 7) % Tt;
    const int n  = bid / (7 * Tt);
    const int h0 = hb * 8;

    f32x16 acc[2][2] = {};

#pragma unroll 1
    for (int cih = 0; cih < 2; ++cih) {
#pragma unroll 1
      for (int kd = 0; kd < 3; ++kd) {
        const int td = t + kd - 1;
        if (td < 0 || td >= Tt) continue;
        __builtin_amdgcn_sched_barrier(0);
        __builtin_amdgcn_s_barrier();
        __builtin_amdgcn_sched_barrier(0);
        // stage A: 2320 chunks
        {
          const size_t tdbase = (size_t)(n * Tt + td) * ((size_t)Hh * Ww * Cc);
#pragma unroll
          for (int it = 0; it < 5; ++it) {
            int fi = it * 512 + tid;
            int u = fi / 232, c = fi - u * 232;
            int r = c >> 2, slot = c & 3;
            int hh = h0 - 1 + u;
            int slog = slot ^ ((r >> 1) & 3);
            const u16* src = a + tdbase
                + ((size_t)hh * Ww + (r - 1)) * Cc + cih * 32 + slog * 8;
            bool valid = (fi < 2320) & (hh >= 0) & (hh < Hh) & (r >= 1) & (r <= Ww);
            if (!valid) src = zpage;
            gload16(src, As + (it * 512 + wbase) * 16);
          }
        }
        // stage B: 2304 chunks (hi only)
        {
#pragma unroll
          for (int it = 0; it < 5; ++it) {
            int fi = it * 512 + tid;
            int u = fi >> 8, c = fi & 255;
            int co = c >> 2, slot = c & 3;
            int slog = slot ^ ((co >> 1) & 3);
            const u16* src = w2h + (kd * 9 + u) * 4096 + co * 64 + cih * 32 + slog * 8;
            if (fi >= 2304) src = zpage;
            gload16(src, Bs + (it * 512 + wbase) * 16);
          }
        }
        asm volatile("s_waitcnt vmcnt(0)" ::: "memory");
        __builtin_amdgcn_s_barrier();
        __builtin_amdgcn_sched_barrier(0);
        const char* Ab0 = As + (size_t)wid * SLICE_B;
#pragma unroll
        for (int kh = 0; kh < 3; ++kh) {
          const char* Ab = Ab0 + (size_t)kh * SLICE_B;
#pragma unroll
          for (int kw = 0; kw < 3; ++kw) {
            const int tap9 = kh * 3 + kw;
            bf16x8 a2[2][2], bh[2][2];
#pragma unroll
            for (int m = 0; m < 2; ++m)
#pragma unroll
              for (int kk = 0; kk < 2; ++kk)
                a2[m][kk] = *frag_ptr(Ab, l31 + 32 * m + kw, kk * 2 + hi5);
#pragma unroll
            for (int nt = 0; nt < 2; ++nt)
#pragma unroll
              for (int kk = 0; kk < 2; ++kk)
                bh[nt][kk] = *frag_ptr(Bs + tap9 * 4096, l31 + 32 * nt, kk * 2 + hi5);
#pragma unroll
            for (int m = 0; m < 2; ++m)
#pragma unroll
              for (int nt = 0; nt < 2; ++nt)
#pragma unroll
                for (int kk = 0; kk < 2; ++kk)
                  acc[m][nt] = __builtin_amdgcn_mfma_f32_32x32x16_bf16(
                      a2[m][kk], bh[nt][kk], acc[m][nt], 0, 0, 0);
          }
        }
      }
    }
    // epilogue: conv-quant + identity-quant + relu -> f32 out (NCDHW)
    const int h = h0 + wid;
#pragma unroll
    for (int nt = 0; nt < 2; ++nt) {
      int co = 32 * nt + l31;
      float e = e2[co];
      float sc = exp2f(7.0f - e), inv = exp2f(e - 7.0f);
      float bias = b2[co];
#pragma unroll
      for (int m = 0; m < 2; ++m)
#pragma unroll
        for (int reg = 0; reg < 16; ++reg) {
          int w = 32 * m + (reg & 3) + 8 * (reg >> 2) + 4 * hi5;
          if (w < Ww) {
            float v = acc[m][nt][reg] + bias;
            float q = rintf(v * sc);
            q = fminf(fmaxf(q, -127.f), 127.f);
            v = q * inv;
            size_t xi = (((size_t)(n * Cc + co) * Tt + t) * Hh + h) * Ww + w;
            float xv = x[xi];
            float qx = rintf(xv * sc);
            qx = fminf(fmaxf(qx, -127.f), 127.f);
            out[xi] = fmaxf(qx * inv + v, 0.0f);
          }
        }
    }
}

extern "C" void kernel_launch(void* const* d_in, const int* in_sizes, int n_in,
                              void* d_out, int out_size, void* d_ws, size_t ws_size,
                              hipStream_t stream) {
    const float* x  = (const float*)d_in[0];
    const float* w1 = (const float*)d_in[1];
    const float* b1 = (const float*)d_in[2];
    const float* w2 = (const float*)d_in[3];
    const float* b2 = (const float*)d_in[4];
    const float* e1 = (const float*)d_in[5];
    const float* e2 = (const float*)d_in[6];

    u16* xh = (u16*)d_out;                 // d_out doubles as xh scratch
    char* ws = (char*)d_ws;
    u16* w1h = (u16*)(ws);
    u16* w1l = (u16*)(ws + 221184);
    u16* w2h = (u16*)(ws + 442368);
    u16* w2l = (u16*)(ws + 663552);
    u16* zpage = (u16*)(ws + 884736);      // 4KB zeros
    u16* res1  = (u16*)(ws + 888832);      // 51.4 MB

    prep_w_kernel<<<865, 256, 0, stream>>>(w1, w2, w1h, w1l, w2h, w2l, zpage);
    split_x_kernel<<<Nn * Tt * Hh, 256, 0, stream>>>(x, xh);
    conv1_mfma_kernel<<<896, 512, 0, stream>>>(xh, w1h, w1l, b1, e1, zpage, res1);
    conv2_mfma_kernel<<<896, 512, 0, stream>>>(res1, w2h, b2, e2, x, zpage, (float*)d_out);
}

// Round 13
// 341.879 us; speedup vs baseline: 1.2185x; 1.0373x over previous
//
#include <hip/hip_runtime.h>
#include <hip/hip_bf16.h>

#define Nn 8
#define Cc 64
#define Tt 16
#define Hh 56
#define Ww 56

typedef __bf16 bf16x8 __attribute__((ext_vector_type(8)));
typedef float f32x16 __attribute__((ext_vector_type(16)));
typedef unsigned short u16;
typedef unsigned int u32;

__device__ __forceinline__ u16 f32_to_bf16(float f) {
    u32 u = __float_as_uint(f);
    u32 r = (u + 0x7FFFu + ((u >> 16) & 1u)) >> 16;
    return (u16)r;
}
__device__ __forceinline__ float bf16_to_f32(u16 h) {
    return __uint_as_float(((u32)h) << 16);
}

// async global->LDS, 16B per lane, dst = wave-uniform base + lane*16
__device__ __forceinline__ void gload16(const void* gsrc, void* lds) {
    __builtin_amdgcn_global_load_lds(
        (const __attribute__((address_space(1))) u32*)gsrc,
        (__attribute__((address_space(3))) u32*)lds, 16, 0, 0);
}

// ---------------- P0: weights -> bf16 hi/lo in [tap][co][ci]; +zeros page ----
__global__ __launch_bounds__(256) void prep_w_kernel(
    const float* __restrict__ w1, const float* __restrict__ w2,
    u16* __restrict__ w1h, u16* __restrict__ w1l,
    u16* __restrict__ w2h, u16* __restrict__ w2l,
    u16* __restrict__ zpage)
{
    int idx = blockIdx.x * 256 + threadIdx.x;
    if (idx >= 221184) {                            // zeros page: 256 x 16B = 4KB
        ((uint4*)zpage)[idx - 221184] = make_uint4(0, 0, 0, 0);
        return;
    }
    int conv = idx / 110592;
    int rem  = idx % 110592;
    int tap  = rem >> 12;
    int co   = (rem >> 6) & 63;
    int ci   = rem & 63;
    const float* w = conv ? w2 : w1;
    float v = w[co * 1728 + ci * 27 + tap];
    u16 hi = f32_to_bf16(v);
    u16 lo = f32_to_bf16(v - bf16_to_f32(hi));
    int dst = tap * 4096 + co * 64 + ci;
    if (conv) { w2h[dst] = hi; w2l[dst] = lo; }
    else      { w1h[dst] = hi; w1l[dst] = lo; }
}

// ---------------- P1: x -> xh bf16 in [n][t][h][w][ci] (hi only) ----------------
__global__ __launch_bounds__(256) void split_x_kernel(
    const float* __restrict__ x, u16* __restrict__ xh)
{
    __shared__ float tile[Cc][Hh + 1];
    const int tid = threadIdx.x;
    const int bid = blockIdx.x;           // = (n*Tt + t)*Hh + h
    const int h = bid % Hh;
    const int t = (bid / Hh) % Tt;
    const int n = bid / (Hh * Tt);
    for (int it = 0; it < 14; ++it) {
        int id = it * 256 + tid;
        int ci = id / Ww, w = id % Ww;
        tile[ci][w] = x[(((size_t)(n * Cc + ci) * Tt + t) * Hh + h) * Ww + w];
    }
    __syncthreads();
    const size_t obase = (size_t)bid * (Ww * Cc);
    for (int it = 0; it < 7; ++it) {
        int j = it * 256 + tid;
        int w = j >> 5, ci0 = (j & 31) << 1;
        u16 h0 = f32_to_bf16(tile[ci0][w]);
        u16 h1 = f32_to_bf16(tile[ci0 + 1][w]);
        *(ushort2*)(xh + obase + (size_t)w * Cc + ci0) = make_ushort2(h0, h1);
    }
}

// ---------------- conv kernels ----------------
// A slice: 58 rows (x-pos -1..56) x 64B (32 ci). Chunk fi -> LDS byte fi*16 (LINEAR).
// XOR swizzle on global SOURCE index; reads apply the same XOR.
#define SLICE_B 3712                  // 58*64
#define A1_BUF  40960                 // 2320 data chunks + pad
#define B1_BUF  36864                 // 9 taps x 4096 (one hl)
#define C1_SMEM (2 * A1_BUF + 2 * B1_BUF)   // 155648
#define C2_BOFF 40960
#define C2_SMEM 81920                 // 2 blocks/CU

__device__ __forceinline__ const bf16x8* frag_ptr(const char* base, int row, int slot) {
    int col = (slot * 16) ^ (((row >> 1) & 3) << 4);
    return (const bf16x8*)(base + row * 64 + col);
}

// conv1: 2-pass (xh*wh, xh*wl), 32x32x16 MFMA, A+B double-buffered, 12 sub-slabs
__global__ __launch_bounds__(512, 1) void conv1_mfma_kernel(
    const u16* __restrict__ xh,
    const u16* __restrict__ w1h, const u16* __restrict__ w1l,
    const float* __restrict__ b1, const float* __restrict__ e1,
    const u16* __restrict__ zpage, u16* __restrict__ res1)
{
    __shared__ __align__(16) char smem[C1_SMEM];

    const int tid = threadIdx.x;
    const int l = tid & 63, wid = tid >> 6;
    const int l31 = l & 31, hi5 = l >> 5;
    const int wbase = tid & ~63;                    // wave-uniform
    const int bid = (blockIdx.x & 7) * 112 + (blockIdx.x >> 3);
    const int hb = bid % 7;
    const int t  = (bid / 7) % Tt;
    const int n  = bid / (7 * Tt);
    const int h0 = hb * 8;

    f32x16 acc[2][2] = {};

    // issue A gloads for slab (cih,kd): 2560 chunks (2320 data + pad)
    auto ISSUE_A = [&](int slab, int abuf) {
        char* dst = smem + abuf * A1_BUF;
        const int cih = slab / 3, kd = slab % 3;
        const int td = t + kd - 1;
        const bool tdv = (td >= 0 && td < Tt);
        const size_t tdbase = (size_t)(n * Tt + (tdv ? td : 0)) * ((size_t)Hh * Ww * Cc);
#pragma unroll
        for (int it = 0; it < 5; ++it) {
            int fi = it * 512 + tid;
            int u = fi / 232, c = fi - u * 232;
            int r = c >> 2, slot = c & 3;
            int hh = h0 - 1 + u;
            int slog = slot ^ ((r >> 1) & 3);       // pre-swizzled source
            const u16* src = xh + tdbase
                + ((size_t)hh * Ww + (r - 1)) * Cc + cih * 32 + slog * 8;
            bool valid = tdv & (fi < 2320) & (hh >= 0) & (hh < Hh) & (r >= 1) & (r <= Ww);
            if (!valid) src = zpage;
            gload16(src, dst + (it * 512 + wbase) * 16);
        }
    };
    // issue B gloads for sub-slab (cih,kd,hl): 2304 chunks
    auto ISSUE_B = [&](int sub, int bbuf) {
        char* dst = smem + 2 * A1_BUF + bbuf * B1_BUF;
        const int slab = sub >> 1, hl = sub & 1;
        const int cih = slab / 3, kd = slab % 3;
        const u16* wsrc = hl ? w1l : w1h;
#pragma unroll
        for (int it = 0; it < 5; ++it) {
            int fi = it * 512 + tid;
            if (fi < 2304) {
                int u = fi >> 8, c = fi & 255;
                int co = c >> 2, slot = c & 3;
                int slog = slot ^ ((co >> 1) & 3);
                const u16* src = wsrc + (kd * 9 + u) * 4096 + co * 64 + cih * 32 + slog * 8;
                gload16(src, dst + (it * 512 + wbase) * 16);
            }
        }
    };

    // prologue: prime A0, B0
    ISSUE_A(0, 0);
    ISSUE_B(0, 0);
    asm volatile("s_waitcnt vmcnt(0)" ::: "memory");
    __builtin_amdgcn_s_barrier();
    __builtin_amdgcn_sched_barrier(0);

#pragma unroll 1
    for (int j = 0; j < 12; ++j) {
        // prefetch: next B always; next A when entering new slab (j odd)
        if (j < 11) ISSUE_B(j + 1, (j + 1) & 1);
        if ((j & 1) && (j < 11)) ISSUE_A((j + 1) >> 1, ((j + 1) >> 1) & 1);
        __builtin_amdgcn_sched_barrier(0);
        // compute sub-slab j from A buf (j>>1)&1, B buf j&1
        const char* Acur = smem + (((j >> 1) & 1) * A1_BUF);
        const char* Bcur = smem + 2 * A1_BUF + ((j & 1) * B1_BUF);
        const char* Aw = Acur + (size_t)wid * SLICE_B;
#pragma unroll
        for (int kh = 0; kh < 3; ++kh) {
            const char* Ak = Aw + (size_t)kh * SLICE_B;
#pragma unroll
            for (int kw = 0; kw < 3; ++kw) {
                const int tap9 = kh * 3 + kw;
                bf16x8 a[2][2], b[2][2];
#pragma unroll
                for (int m = 0; m < 2; ++m)
#pragma unroll
                    for (int kk = 0; kk < 2; ++kk)
                        a[m][kk] = *frag_ptr(Ak, l31 + 32 * m + kw, kk * 2 + hi5);
#pragma unroll
                for (int nt = 0; nt < 2; ++nt)
#pragma unroll
                    for (int kk = 0; kk < 2; ++kk)
                        b[nt][kk] = *frag_ptr(Bcur + tap9 * 4096, l31 + 32 * nt, kk * 2 + hi5);
                __builtin_amdgcn_s_setprio(1);
#pragma unroll
                for (int m = 0; m < 2; ++m)
#pragma unroll
                    for (int nt = 0; nt < 2; ++nt)
#pragma unroll
                        for (int kk = 0; kk < 2; ++kk)
                            acc[m][nt] = __builtin_amdgcn_mfma_f32_32x32x16_bf16(
                                a[m][kk], b[nt][kk], acc[m][nt], 0, 0, 0);
                __builtin_amdgcn_s_setprio(0);
            }
        }
        __builtin_amdgcn_sched_barrier(0);
        __builtin_amdgcn_s_barrier();               // all waves done reading bufs
        asm volatile("s_waitcnt vmcnt(0)" ::: "memory");  // prefetches landed
        __builtin_amdgcn_s_barrier();
        __builtin_amdgcn_sched_barrier(0);
    }

    // epilogue: bias, BFP quant, relu, store bf16 (exact)
    const int h = h0 + wid;
    const size_t rowbase = ((size_t)(n * Tt + t) * Hh + h) * ((size_t)Ww * Cc);
#pragma unroll
    for (int nt = 0; nt < 2; ++nt) {
        int co = 32 * nt + l31;
        float e = e1[co];
        float sc = exp2f(7.0f - e), inv = exp2f(e - 7.0f);
        float bias = b1[co];
#pragma unroll
        for (int m = 0; m < 2; ++m)
#pragma unroll
            for (int reg = 0; reg < 16; ++reg) {
                int w = 32 * m + (reg & 3) + 8 * (reg >> 2) + 4 * hi5;
                if (w < Ww) {
                    float v = acc[m][nt][reg] + bias;
                    float q = rintf(v * sc);
                    q = fminf(fmaxf(q, -127.f), 127.f);
                    v = fmaxf(q * inv, 0.0f);
                    res1[rowbase + (size_t)w * Cc + co] = f32_to_bf16(v);
                }
            }
    }
}

// conv2: single-pass (a.w2h), 32x32x16 MFMA, 80KB LDS -> 2 blocks/CU
__global__ __launch_bounds__(512, 2) void conv2_mfma_kernel(
    const u16* __restrict__ a, const u16* __restrict__ w2h,
    const float* __restrict__ b2, const float* __restrict__ e2,
    const float* __restrict__ x, const u16* __restrict__ zpage,
    float* __restrict__ out)
{
    __shared__ __align__(16) char smem[C2_SMEM];
    char* As = smem;
    char* Bs = smem + C2_BOFF;

    const int tid = threadIdx.x;
    const int l = tid & 63, wid = tid >> 6;
    const int l31 = l & 31, hi5 = l >> 5;
    const int wbase = tid & ~63;
    const int bid = (blockIdx.x & 7) * 112 + (blockIdx.x >> 3);
    const int hb = bid % 7;
    const int t  = (bid / 7) % Tt;
    const int n  = bid / (7 * Tt);
    const int h0 = hb * 8;

    f32x16 acc[2][2] = {};

#pragma unroll 1
    for (int cih = 0; cih < 2; ++cih) {
#pragma unroll 1
      for (int kd = 0; kd < 3; ++kd) {
        const int td = t + kd - 1;
        if (td < 0 || td >= Tt) continue;
        __builtin_amdgcn_sched_barrier(0);
        __builtin_amdgcn_s_barrier();
        __builtin_amdgcn_sched_barrier(0);
        // stage A: 2320 chunks
        {
          const size_t tdbase = (size_t)(n * Tt + td) * ((size_t)Hh * Ww * Cc);
#pragma unroll
          for (int it = 0; it < 5; ++it) {
            int fi = it * 512 + tid;
            int u = fi / 232, c = fi - u * 232;
            int r = c >> 2, slot = c & 3;
            int hh = h0 - 1 + u;
            int slog = slot ^ ((r >> 1) & 3);
            const u16* src = a + tdbase
                + ((size_t)hh * Ww + (r - 1)) * Cc + cih * 32 + slog * 8;
            bool valid = (fi < 2320) & (hh >= 0) & (hh < Hh) & (r >= 1) & (r <= Ww);
            if (!valid) src = zpage;
            gload16(src, As + (it * 512 + wbase) * 16);
          }
        }
        // stage B: 2304 chunks (hi only)
        {
#pragma unroll
          for (int it = 0; it < 5; ++it) {
            int fi = it * 512 + tid;
            int u = fi >> 8, c = fi & 255;
            int co = c >> 2, slot = c & 3;
            int slog = slot ^ ((co >> 1) & 3);
            const u16* src = w2h + (kd * 9 + u) * 4096 + co * 64 + cih * 32 + slog * 8;
            if (fi >= 2304) src = zpage;
            gload16(src, Bs + (it * 512 + wbase) * 16);
          }
        }
        asm volatile("s_waitcnt vmcnt(0)" ::: "memory");
        __builtin_amdgcn_s_barrier();
        __builtin_amdgcn_sched_barrier(0);
        const char* Ab0 = As + (size_t)wid * SLICE_B;
#pragma unroll
        for (int kh = 0; kh < 3; ++kh) {
          const char* Ab = Ab0 + (size_t)kh * SLICE_B;
#pragma unroll
          for (int kw = 0; kw < 3; ++kw) {
            const int tap9 = kh * 3 + kw;
            bf16x8 a2[2][2], bh[2][2];
#pragma unroll
            for (int m = 0; m < 2; ++m)
#pragma unroll
              for (int kk = 0; kk < 2; ++kk)
                a2[m][kk] = *frag_ptr(Ab, l31 + 32 * m + kw, kk * 2 + hi5);
#pragma unroll
            for (int nt = 0; nt < 2; ++nt)
#pragma unroll
              for (int kk = 0; kk < 2; ++kk)
                bh[nt][kk] = *frag_ptr(Bs + tap9 * 4096, l31 + 32 * nt, kk * 2 + hi5);
            __builtin_amdgcn_s_setprio(1);
#pragma unroll
            for (int m = 0; m < 2; ++m)
#pragma unroll
              for (int nt = 0; nt < 2; ++nt)
#pragma unroll
                for (int kk = 0; kk < 2; ++kk)
                  acc[m][nt] = __builtin_amdgcn_mfma_f32_32x32x16_bf16(
                      a2[m][kk], bh[nt][kk], acc[m][nt], 0, 0, 0);
            __builtin_amdgcn_s_setprio(0);
          }
        }
      }
    }
    // epilogue: conv-quant + identity-quant + relu -> f32 out (NCDHW)
    const int h = h0 + wid;
#pragma unroll
    for (int nt = 0; nt < 2; ++nt) {
      int co = 32 * nt + l31;
      float e = e2[co];
      float sc = exp2f(7.0f - e), inv = exp2f(e - 7.0f);
      float bias = b2[co];
#pragma unroll
      for (int m = 0; m < 2; ++m)
#pragma unroll
        for (int reg = 0; reg < 16; ++reg) {
          int w = 32 * m + (reg & 3) + 8 * (reg >> 2) + 4 * hi5;
          if (w < Ww) {
            float v = acc[m][nt][reg] + bias;
            float q = rintf(v * sc);
            q = fminf(fmaxf(q, -127.f), 127.f);
            v = q * inv;
            size_t xi = (((size_t)(n * Cc + co) * Tt + t) * Hh + h) * Ww + w;
            float xv = x[xi];
            float qx = rintf(xv * sc);
            qx = fminf(fmaxf(qx, -127.f), 127.f);
            out[xi] = fmaxf(qx * inv + v, 0.0f);
          }
        }
    }
}

extern "C" void kernel_launch(void* const* d_in, const int* in_sizes, int n_in,
                              void* d_out, int out_size, void* d_ws, size_t ws_size,
                              hipStream_t stream) {
    const float* x  = (const float*)d_in[0];
    const float* w1 = (const float*)d_in[1];
    const float* b1 = (const float*)d_in[2];
    const float* w2 = (const float*)d_in[3];
    const float* b2 = (const float*)d_in[4];
    const float* e1 = (const float*)d_in[5];
    const float* e2 = (const float*)d_in[6];

    u16* xh = (u16*)d_out;                 // d_out doubles as xh scratch
    char* ws = (char*)d_ws;
    u16* w1h = (u16*)(ws);
    u16* w1l = (u16*)(ws + 221184);
    u16* w2h = (u16*)(ws + 442368);
    u16* w2l = (u16*)(ws + 663552);
    u16* zpage = (u16*)(ws + 884736);      // 4KB zeros
    u16* res1  = (u16*)(ws + 888832);      // 51.4 MB

    prep_w_kernel<<<865, 256, 0, stream>>>(w1, w2, w1h, w1l, w2h, w2l, zpage);
    split_x_kernel<<<Nn * Tt * Hh, 256, 0, stream>>>(x, xh);
    conv1_mfma_kernel<<<896, 512, 0, stream>>>(xh, w1h, w1l, b1, e1, zpage, res1);
    conv2_mfma_kernel<<<896, 512, 0, stream>>>(res1, w2h, b2, e2, x, zpage, (float*)d_out);
}